// Round 1
// baseline (1521.619 us; speedup 1.0000x reference)
//
#include <hip/hip_runtime.h>
#include <hip/hip_bf16.h>

#define MTOT 4096   // B*S
#define DD   1024
#define D2   2048
#define SS   2048
#define BB   2
#define NC   16
#define CL   (SS/NC)   // 128

__device__ __forceinline__ float geluf(float v){
    return 0.5f*v*(1.0f+erff(v*0.70710678118654752f));
}
__device__ __forceinline__ float sigmf(float v){
    return 1.0f/(1.0f+expf(-v));
}

// ACT: 0 none, 1 gelu, 2 sigmoid, 3 sigmoid*5, 4 sigmoid(v*scale)
template<int ACT, bool RESID>
__global__ __launch_bounds__(256) void gemm_k(
    const float* __restrict__ A, const float* __restrict__ Bm,
    const float* __restrict__ bias, const float* __restrict__ scaleptr,
    const float* __restrict__ resid, float* __restrict__ C,
    int M, int N, int K)
{
    __shared__ float As[16][64];
    __shared__ float Bs[16][64];
    int tid = threadIdx.x;
    int tx = tid & 15, ty = tid >> 4;
    int m0 = blockIdx.y*64, n0 = blockIdx.x*64;
    float acc[4][4] = {};
    int arow = tid>>2, akq = (tid&3)<<2;
    int brow = tid>>4, bnq = (tid&15)<<2;
    const float* Aptr = A + (size_t)(m0+arow)*K + akq;
    const float* Bptr = Bm + (size_t)brow*N + n0 + bnq;
    for(int k0=0;k0<K;k0+=16){
        float4 a4 = *(const float4*)(Aptr + k0);
        float4 b4 = *(const float4*)(Bptr + (size_t)k0*N);
        __syncthreads();
        As[akq+0][arow]=a4.x; As[akq+1][arow]=a4.y;
        As[akq+2][arow]=a4.z; As[akq+3][arow]=a4.w;
        *(float4*)&Bs[brow][bnq] = b4;
        __syncthreads();
        #pragma unroll
        for(int kk=0;kk<16;kk++){
            float4 av = *(const float4*)&As[kk][ty<<2];
            float4 bv = *(const float4*)&Bs[kk][tx<<2];
            float am[4]={av.x,av.y,av.z,av.w};
            float bn[4]={bv.x,bv.y,bv.z,bv.w};
            #pragma unroll
            for(int i=0;i<4;i++)
                #pragma unroll
                for(int j=0;j<4;j++)
                    acc[i][j] = fmaf(am[i], bn[j], acc[i][j]);
        }
    }
    float sc = (ACT==4) ? scaleptr[0] : 1.0f;
    #pragma unroll
    for(int i=0;i<4;i++){
        int m = m0 + (ty<<2) + i;
        int n = n0 + (tx<<2);
        float4 o;
        float* op = &o.x;
        #pragma unroll
        for(int j=0;j<4;j++){
            float v = acc[i][j] + bias[n+j];
            if(ACT==1) v = geluf(v);
            else if(ACT==2) v = sigmf(v);
            else if(ACT==3) v = sigmf(v)*5.0f;
            else if(ACT==4) v = sigmf(v*sc);
            if(RESID) v += resid[(size_t)m*N + n + j];
            op[j]=v;
        }
        *(float4*)(C + (size_t)m*N + n) = o;
    }
}

// ---- scans ----
// grid: (DD/256, NC, BB)
__global__ __launch_bounds__(256) void scan1_phi_k(
    const float* __restrict__ pd, const float* __restrict__ iscale, float* __restrict__ csum)
{
    int d = blockIdx.x*256 + threadIdx.x;
    int c = blockIdx.y, b = blockIdx.z;
    float scv = fabsf(iscale[d]);
    const float* p = pd + ((size_t)b*SS + (size_t)c*CL)*DD + d;
    float s=0.f;
    for(int i=0;i<CL;i++) s += p[(size_t)i*DD]*scv;
    csum[((size_t)b*NC + c)*DD + d] = s;
}

// exclusive scan over NC chunk-sums; layout [nch][NC][DD] per chain-group
__global__ void scan2_k(float* __restrict__ csum, int nchains){
    int idx = blockIdx.x*256 + threadIdx.x;
    if(idx>=nchains) return;
    int xg = idx / DD, d = idx % DD;
    float* p = csum + (size_t)xg*NC*DD + d;
    float run=0.f;
    for(int c=0;c<NC;c++){ float t=p[(size_t)c*DD]; p[(size_t)c*DD]=run; run+=t; }
}

__global__ __launch_bounds__(256) void scan3_phi_k(
    float* __restrict__ pd, const float* __restrict__ iscale, const float* __restrict__ csum)
{
    int d = blockIdx.x*256 + threadIdx.x;
    int c = blockIdx.y, b = blockIdx.z;
    float scv = fabsf(iscale[d]);
    float* p = pd + ((size_t)b*SS + (size_t)c*CL)*DD + d;
    float run = csum[((size_t)b*NC + c)*DD + d];
    for(int i=0;i<CL;i++){ run += p[(size_t)i*DD]*scv; p[(size_t)i*DD]=run; }
}

__global__ __launch_bounds__(256) void scan1_tri_k(
    const float* __restrict__ tr, const float* __restrict__ ti, const float* __restrict__ tw,
    float* __restrict__ csum)
{
    int d = blockIdx.x*256 + threadIdx.x;
    int c = blockIdx.y, b = blockIdx.z;
    size_t off = ((size_t)b*SS + (size_t)c*CL)*DD + d;
    float s0=0.f,s1=0.f,s2=0.f;
    for(int i=0;i<CL;i++){
        size_t o = off + (size_t)i*DD;
        s0 += tr[o]; s1 += ti[o]; s2 += tw[o];
    }
    size_t cs = ((size_t)b*NC + c)*DD + d;
    size_t G = (size_t)BB*NC*DD;
    csum[cs]=s0; csum[G+cs]=s1; csum[2*G+cs]=s2;
}

__global__ __launch_bounds__(256) void scan3_tri_k(
    float* __restrict__ tr, float* __restrict__ ti, float* __restrict__ tw,
    const float* __restrict__ csum)
{
    int d = blockIdx.x*256 + threadIdx.x;
    int c = blockIdx.y, b = blockIdx.z;
    size_t off = ((size_t)b*SS + (size_t)c*CL)*DD + d;
    size_t cs = ((size_t)b*NC + c)*DD + d;
    size_t G = (size_t)BB*NC*DD;
    float r0=csum[cs], r1=csum[G+cs], r2=csum[2*G+cs];
    for(int i=0;i<CL;i++){
        size_t o = off + (size_t)i*DD;
        r0 += tr[o]; tr[o]=r0;
        r1 += ti[o]; ti[o]=r1;
        r2 += tw[o]; tw[o]=r2;
    }
}

// elementwise: content & phase terms
__global__ __launch_bounds__(256) void elemw1_k(
    const float* __restrict__ wg, const float* __restrict__ mag,
    const float* __restrict__ x,  const float* __restrict__ phi,
    float* __restrict__ tr, float* __restrict__ ti, float* __restrict__ tw)
{
    size_t i = (size_t)blockIdx.x*256 + threadIdx.x;
    float w=wg[i], m=mag[i];
    float c = w*x[i]*m;
    float sp,cp; sincosf(phi[i], &sp, &cp);
    tr[i]=c*cp; ti[i]=c*sp; tw[i]=fmaf(w,m,1e-8f);
}

// retrieval + mix + LayerNorm; one row (b,s) per block
__global__ __launch_bounds__(256) void retrieve_ln_k(
    const float* __restrict__ tr, const float* __restrict__ ti, const float* __restrict__ tw,
    const float* __restrict__ phi, const float* __restrict__ qadj, const float* __restrict__ mix,
    const float* __restrict__ ln_g, const float* __restrict__ ln_b, float* __restrict__ outp)
{
    int row = blockIdx.x;
    size_t base  = (size_t)row*DD;
    size_t mbase = (size_t)row*D2;
    float vals[4];
    float sum=0.f, sumsq=0.f;
    #pragma unroll
    for(int k=0;k<4;k++){
        int d = threadIdx.x + k*256;
        float inv = rsqrtf(tw[base+d]);
        float mr = tr[base+d]*inv, mi = ti[base+d]*inv;
        float qp = phi[base+d] + qadj[base+d];
        float sq, cq; sincosf(qp, &sq, &cq);
        float rr = mr*cq + mi*sq;
        float ri = mi*cq - mr*sq;
        float ret = mix[mbase+d]*rr + mix[mbase+DD+d]*ri;
        vals[k]=ret; sum+=ret; sumsq = fmaf(ret,ret,sumsq);
    }
    #pragma unroll
    for(int off=32;off;off>>=1){
        sum   += __shfl_down(sum,off);
        sumsq += __shfl_down(sumsq,off);
    }
    __shared__ float red[8];
    int lane = threadIdx.x & 63, wid = threadIdx.x >> 6;
    if(lane==0){ red[wid]=sum; red[4+wid]=sumsq; }
    __syncthreads();
    sum   = red[0]+red[1]+red[2]+red[3];
    sumsq = red[4]+red[5]+red[6]+red[7];
    float mu  = sum * (1.0f/DD);
    float var = sumsq*(1.0f/DD) - mu*mu;
    float rstd = rsqrtf(var + 1e-5f);
    #pragma unroll
    for(int k=0;k<4;k++){
        int d = threadIdx.x + k*256;
        outp[base+d] = (vals[k]-mu)*rstd*ln_g[d] + ln_b[d];
    }
}

extern "C" void kernel_launch(void* const* d_in, const int* in_sizes, int n_in,
                              void* d_out, int out_size, void* d_ws, size_t ws_size,
                              hipStream_t stream)
{
    const float* x     = (const float*)d_in[0];
    const float* w_pt1 = (const float*)d_in[1];
    const float* b_pt1 = (const float*)d_in[2];
    const float* w_pt2 = (const float*)d_in[3];
    const float* b_pt2 = (const float*)d_in[4];
    const float* iscale= (const float*)d_in[5];
    const float* w_wg  = (const float*)d_in[6];
    const float* b_wg  = (const float*)d_in[7];
    const float* gtemp = (const float*)d_in[8];
    const float* w_mag = (const float*)d_in[9];
    const float* b_mag = (const float*)d_in[10];
    const float* w_q1  = (const float*)d_in[11];
    const float* b_q1  = (const float*)d_in[12];
    const float* w_q2  = (const float*)d_in[13];
    const float* b_q2  = (const float*)d_in[14];
    const float* w_mix = (const float*)d_in[15];
    const float* b_mix = (const float*)d_in[16];
    const float* ln_g  = (const float*)d_in[17];
    const float* ln_b  = (const float*)d_in[18];
    const float* w_o1  = (const float*)d_in[19];
    const float* b_o1  = (const float*)d_in[20];
    const float* w_o2  = (const float*)d_in[21];
    const float* b_o2  = (const float*)d_in[22];
    float* out = (float*)d_out;

    float* ws = (float*)d_ws;
    const size_t SZ = (size_t)MTOT*DD;     // 4M floats
    float* H1   = ws;                      // 2*SZ  (later: tr = H1, ti = H1+SZ)
    float* pd   = ws + 2*SZ;               // SZ    (becomes phi in-place)
    float* wg   = ws + 3*SZ;               // SZ    (later: ln)
    float* mag  = ws + 4*SZ;               // SZ    (later: Ho)
    float* Hq   = ws + 5*SZ;               // SZ    (later: tw)
    float* qadj = ws + 6*SZ;               // SZ
    float* mixb = ws + 7*SZ;               // 2*SZ
    float* csum_phi = ws + 9*SZ;           // BB*NC*DD = 32768
    float* csum_tri = csum_phi + (size_t)BB*NC*DD;  // 3*BB*NC*DD
    float* tr = H1; float* ti = H1 + SZ; float* tw = Hq;
    float* ln = wg; float* Ho = mag;

    dim3 blk(256);
    // 1. H1 = gelu(x @ w_pt1 + b_pt1)
    gemm_k<1,false><<<dim3(D2/64, MTOT/64), blk, 0, stream>>>(x, w_pt1, b_pt1, nullptr, nullptr, H1, MTOT, D2, DD);
    // 2. pd = H1 @ w_pt2 + b_pt2
    gemm_k<0,false><<<dim3(DD/64, MTOT/64), blk, 0, stream>>>(H1, w_pt2, b_pt2, nullptr, nullptr, pd, MTOT, DD, D2);
    // 3. wg = sigmoid((x @ w_wg + b_wg) * gate_temp)
    gemm_k<4,false><<<dim3(DD/64, MTOT/64), blk, 0, stream>>>(x, w_wg, b_wg, gtemp, nullptr, wg, MTOT, DD, DD);
    // 4. mag = sigmoid(x @ w_mag + b_mag) * 5
    gemm_k<3,false><<<dim3(DD/64, MTOT/64), blk, 0, stream>>>(x, w_mag, b_mag, nullptr, nullptr, mag, MTOT, DD, DD);
    // 5. Hq = gelu(x @ w_q1 + b_q1)
    gemm_k<1,false><<<dim3(DD/64, MTOT/64), blk, 0, stream>>>(x, w_q1, b_q1, nullptr, nullptr, Hq, MTOT, DD, DD);
    // 6. qadj = Hq @ w_q2 + b_q2
    gemm_k<0,false><<<dim3(DD/64, MTOT/64), blk, 0, stream>>>(Hq, w_q2, b_q2, nullptr, nullptr, qadj, MTOT, DD, DD);
    // 7. mix = sigmoid(x @ w_mix + b_mix)
    gemm_k<2,false><<<dim3(D2/64, MTOT/64), blk, 0, stream>>>(x, w_mix, b_mix, nullptr, nullptr, mixb, MTOT, D2, DD);
    // 8. phi = cumsum(pd * |iscale|) in place
    scan1_phi_k<<<dim3(DD/256, NC, BB), blk, 0, stream>>>(pd, iscale, csum_phi);
    scan2_k<<<dim3((BB*DD+255)/256), blk, 0, stream>>>(csum_phi, BB*DD);
    scan3_phi_k<<<dim3(DD/256, NC, BB), blk, 0, stream>>>(pd, iscale, csum_phi);
    // 9. elementwise terms
    elemw1_k<<<dim3(SZ/256), blk, 0, stream>>>(wg, mag, x, pd, tr, ti, tw);
    // 10. triple cumsum in place
    scan1_tri_k<<<dim3(DD/256, NC, BB), blk, 0, stream>>>(tr, ti, tw, csum_tri);
    scan2_k<<<dim3((3*BB*DD+255)/256), blk, 0, stream>>>(csum_tri, 3*BB*DD);
    scan3_tri_k<<<dim3(DD/256, NC, BB), blk, 0, stream>>>(tr, ti, tw, csum_tri);
    // 11. retrieval + mix + LayerNorm -> ln
    retrieve_ln_k<<<dim3(MTOT), blk, 0, stream>>>(tr, ti, tw, pd, qadj, mixb, ln_g, ln_b, ln);
    // 12. Ho = gelu(ln @ w_o1 + b_o1)
    gemm_k<1,false><<<dim3(DD/64, MTOT/64), blk, 0, stream>>>(ln, w_o1, b_o1, nullptr, nullptr, Ho, MTOT, DD, DD);
    // 13. out = Ho @ w_o2 + b_o2 + x
    gemm_k<0,true><<<dim3(DD/64, MTOT/64), blk, 0, stream>>>(Ho, w_o2, b_o2, nullptr, x, out, MTOT, DD, DD);
}

// Round 2
// 379.158 us; speedup vs baseline: 4.0132x; 4.0132x over previous
//
#include <hip/hip_runtime.h>
#include <hip/hip_bf16.h>

#define MTOT 4096   // B*S
#define DD   1024
#define D2   2048
#define SS   2048
#define BB   2
#define NC   16
#define CL   (SS/NC)   // 128

typedef __attribute__((ext_vector_type(8))) short bf16x8;
typedef __attribute__((ext_vector_type(4))) float f32x4;

__device__ __forceinline__ float geluf(float v){
    return 0.5f*v*(1.0f+erff(v*0.70710678118654752f));
}
__device__ __forceinline__ float sigmf(float v){
    return 1.0f/(1.0f+expf(-v));
}
__device__ __forceinline__ ushort f2bf(float f){
    unsigned u = __float_as_uint(f);
    unsigned r = (u + 0x7FFF + ((u>>16)&1)) >> 16;
    return (ushort)r;
}

// ---------------- bf16 MFMA GEMM core (m97 structure) ----------------
// A: bf16 [M][K] row-major.  Bt: bf16 [N][K] (i.e. W^T).  128x128 tile,
// 4 waves, each wave 64x64 = 4x4 fragments of 16x16x32 MFMA. BK=32.
__device__ __forceinline__ void mgemm_core(
    const ushort* __restrict__ A, const ushort* __restrict__ Bt, int K,
    int m0, int n0, ushort* As, ushort* Bs, f32x4 (&acc)[4][4])
{
    int tid  = threadIdx.x;
    int lane = tid & 63, wave = tid >> 6;
    int wr = wave >> 1, wc = wave & 1;
    int lrow = lane & 15, lk8 = (lane >> 4) << 3;
    for (int k0 = 0; k0 < K; k0 += 32) {
        __syncthreads();   // all waves done reading LDS from prev step
        #pragma unroll
        for (int i = 0; i < 2; i++) {
            int e = (i*256 + tid) * 8;          // elem index in [128][32] tile
            int r = e >> 5, c = e & 31;
            __builtin_amdgcn_global_load_lds(
                (const __attribute__((address_space(1))) void*)(A + (size_t)(m0 + r)*K + k0 + c),
                (__attribute__((address_space(3))) void*)(As + e), 16, 0, 0);
            __builtin_amdgcn_global_load_lds(
                (const __attribute__((address_space(1))) void*)(Bt + (size_t)(n0 + r)*K + k0 + c),
                (__attribute__((address_space(3))) void*)(Bs + e), 16, 0, 0);
        }
        __syncthreads();   // drains vmcnt: staged data visible
        bf16x8 af[4], bfr[4];
        #pragma unroll
        for (int i = 0; i < 4; i++) {
            af[i]  = *(const bf16x8*)(As + (wr*64 + i*16 + lrow)*32 + lk8);
            bfr[i] = *(const bf16x8*)(Bs + (wc*64 + i*16 + lrow)*32 + lk8);
        }
        #pragma unroll
        for (int i = 0; i < 4; i++)
            #pragma unroll
            for (int j = 0; j < 4; j++)
                acc[i][j] = __builtin_amdgcn_mfma_f32_16x16x32_bf16(af[i], bfr[j], acc[i][j], 0, 0, 0);
    }
}

// ACT: 0 none, 1 gelu, 2 sigmoid, 3 sigmoid*5, 4 sigmoid(v*scale)
template<int ACT, bool RESID, bool OUTBF16>
__global__ __launch_bounds__(256) void mgemm_k(
    const ushort* __restrict__ A, const ushort* __restrict__ Bt,
    const float* __restrict__ bias, const float* __restrict__ scaleptr,
    const float* __restrict__ resid, void* __restrict__ Cout,
    int N, int K)
{
    __shared__ ushort As[4096], Bs[4096];
    int m0 = blockIdx.y * 128, n0 = blockIdx.x * 128;
    f32x4 acc[4][4] = {};
    mgemm_core(A, Bt, K, m0, n0, As, Bs, acc);
    int lane = threadIdx.x & 63, wave = threadIdx.x >> 6;
    int wr = wave >> 1, wc = wave & 1;
    float sc = (ACT==4) ? scaleptr[0] : 1.0f;
    #pragma unroll
    for (int i = 0; i < 4; i++) {
        int mb = m0 + wr*64 + i*16 + (lane>>4)*4;
        #pragma unroll
        for (int j = 0; j < 4; j++) {
            int n = n0 + wc*64 + j*16 + (lane&15);
            float bv = bias[n];
            #pragma unroll
            for (int r = 0; r < 4; r++) {
                size_t idx = (size_t)(mb + r)*N + n;
                float v = acc[i][j][r] + bv;
                if (ACT==1) v = geluf(v);
                else if (ACT==2) v = sigmf(v);
                else if (ACT==3) v = sigmf(v)*5.0f;
                else if (ACT==4) v = sigmf(v*sc);
                if (RESID) v += resid[idx];
                if (OUTBF16) ((ushort*)Cout)[idx] = f2bf(v);
                else         ((float*)Cout)[idx]  = v;
            }
        }
    }
}

// batched x@{w_wg,w_mag,w_q1}: z selects weight/bias/activation/output
__global__ __launch_bounds__(256) void mgemm_z3_k(
    const ushort* __restrict__ A,
    const ushort* __restrict__ bt0, const ushort* __restrict__ bt1, const ushort* __restrict__ bt2,
    const float* __restrict__ bias0, const float* __restrict__ bias1, const float* __restrict__ bias2,
    const float* __restrict__ gtemp,
    float* __restrict__ out0, float* __restrict__ out1, ushort* __restrict__ out2,
    int N, int K)
{
    int z = blockIdx.z;
    const ushort* Bt  = (z==0) ? bt0 : (z==1) ? bt1 : bt2;
    const float* bias = (z==0) ? bias0 : (z==1) ? bias1 : bias2;
    __shared__ ushort As[4096], Bs[4096];
    int m0 = blockIdx.y * 128, n0 = blockIdx.x * 128;
    f32x4 acc[4][4] = {};
    mgemm_core(A, Bt, K, m0, n0, As, Bs, acc);
    int lane = threadIdx.x & 63, wave = threadIdx.x >> 6;
    int wr = wave >> 1, wc = wave & 1;
    float sc = gtemp[0];
    #pragma unroll
    for (int i = 0; i < 4; i++) {
        int mb = m0 + wr*64 + i*16 + (lane>>4)*4;
        #pragma unroll
        for (int j = 0; j < 4; j++) {
            int n = n0 + wc*64 + j*16 + (lane&15);
            float bv = bias[n];
            #pragma unroll
            for (int r = 0; r < 4; r++) {
                size_t idx = (size_t)(mb + r)*N + n;
                float v = acc[i][j][r] + bv;
                if (z==0)      out0[idx] = sigmf(v*sc);
                else if (z==1) out1[idx] = sigmf(v)*5.0f;
                else           out2[idx] = f2bf(geluf(v));
            }
        }
    }
}

// ---------------- conversions ----------------
__global__ __launch_bounds__(256) void cvt_bf16_k(const float* __restrict__ in, ushort* __restrict__ outp){
    size_t i = ((size_t)blockIdx.x*256 + threadIdx.x)*8;
    float4 a = *(const float4*)(in + i);
    float4 b = *(const float4*)(in + i + 4);
    ushort t[8];
    t[0]=f2bf(a.x); t[1]=f2bf(a.y); t[2]=f2bf(a.z); t[3]=f2bf(a.w);
    t[4]=f2bf(b.x); t[5]=f2bf(b.y); t[6]=f2bf(b.z); t[7]=f2bf(b.w);
    *(int4*)(outp + i) = *(const int4*)t;
}

// W [K][N] fp32 -> Wt [N][K] bf16, 32x32 tiles
__global__ __launch_bounds__(256) void tcvt_k(const float* __restrict__ W, ushort* __restrict__ Wt, int K, int N){
    __shared__ float tile[32][33];
    int n0 = blockIdx.x*32, k0 = blockIdx.y*32;
    int tx = threadIdx.x & 7, ty = threadIdx.x >> 3;
    float4 v = *(const float4*)(W + (size_t)(k0+ty)*N + n0 + tx*4);
    tile[ty][tx*4+0]=v.x; tile[ty][tx*4+1]=v.y; tile[ty][tx*4+2]=v.z; tile[ty][tx*4+3]=v.w;
    __syncthreads();
    ushort t[4];
    #pragma unroll
    for (int i=0;i<4;i++) t[i] = f2bf(tile[tx*4+i][ty]);
    *(uint2*)(Wt + (size_t)(n0+ty)*K + k0 + tx*4) = *(const uint2*)t;
}

// ---- scans (unchanged from round 1) ----
__global__ __launch_bounds__(256) void scan1_phi_k(
    const float* __restrict__ pd, const float* __restrict__ iscale, float* __restrict__ csum)
{
    int d = blockIdx.x*256 + threadIdx.x;
    int c = blockIdx.y, b = blockIdx.z;
    float scv = fabsf(iscale[d]);
    const float* p = pd + ((size_t)b*SS + (size_t)c*CL)*DD + d;
    float s=0.f;
    for(int i=0;i<CL;i++) s += p[(size_t)i*DD]*scv;
    csum[((size_t)b*NC + c)*DD + d] = s;
}

__global__ void scan2_k(float* __restrict__ csum, int nchains){
    int idx = blockIdx.x*256 + threadIdx.x;
    if(idx>=nchains) return;
    int xg = idx / DD, d = idx % DD;
    float* p = csum + (size_t)xg*NC*DD + d;
    float run=0.f;
    for(int c=0;c<NC;c++){ float t=p[(size_t)c*DD]; p[(size_t)c*DD]=run; run+=t; }
}

__global__ __launch_bounds__(256) void scan3_phi_k(
    float* __restrict__ pd, const float* __restrict__ iscale, const float* __restrict__ csum)
{
    int d = blockIdx.x*256 + threadIdx.x;
    int c = blockIdx.y, b = blockIdx.z;
    float scv = fabsf(iscale[d]);
    float* p = pd + ((size_t)b*SS + (size_t)c*CL)*DD + d;
    float run = csum[((size_t)b*NC + c)*DD + d];
    for(int i=0;i<CL;i++){ run += p[(size_t)i*DD]*scv; p[(size_t)i*DD]=run; }
}

__global__ __launch_bounds__(256) void scan1_tri_k(
    const float* __restrict__ tr, const float* __restrict__ ti, const float* __restrict__ tw,
    float* __restrict__ csum)
{
    int d = blockIdx.x*256 + threadIdx.x;
    int c = blockIdx.y, b = blockIdx.z;
    size_t off = ((size_t)b*SS + (size_t)c*CL)*DD + d;
    float s0=0.f,s1=0.f,s2=0.f;
    for(int i=0;i<CL;i++){
        size_t o = off + (size_t)i*DD;
        s0 += tr[o]; s1 += ti[o]; s2 += tw[o];
    }
    size_t cs = ((size_t)b*NC + c)*DD + d;
    size_t G = (size_t)BB*NC*DD;
    csum[cs]=s0; csum[G+cs]=s1; csum[2*G+cs]=s2;
}

__global__ __launch_bounds__(256) void scan3_tri_k(
    float* __restrict__ tr, float* __restrict__ ti, float* __restrict__ tw,
    const float* __restrict__ csum)
{
    int d = blockIdx.x*256 + threadIdx.x;
    int c = blockIdx.y, b = blockIdx.z;
    size_t off = ((size_t)b*SS + (size_t)c*CL)*DD + d;
    size_t cs = ((size_t)b*NC + c)*DD + d;
    size_t G = (size_t)BB*NC*DD;
    float r0=csum[cs], r1=csum[G+cs], r2=csum[2*G+cs];
    for(int i=0;i<CL;i++){
        size_t o = off + (size_t)i*DD;
        r0 += tr[o]; tr[o]=r0;
        r1 += ti[o]; ti[o]=r1;
        r2 += tw[o]; tw[o]=r2;
    }
}

__global__ __launch_bounds__(256) void elemw1_k(
    const float* __restrict__ wg, const float* __restrict__ mag,
    const float* __restrict__ x,  const float* __restrict__ phi,
    float* __restrict__ tr, float* __restrict__ ti, float* __restrict__ tw)
{
    size_t i = (size_t)blockIdx.x*256 + threadIdx.x;
    float w=wg[i], m=mag[i];
    float c = w*x[i]*m;
    float sp,cp; sincosf(phi[i], &sp, &cp);
    tr[i]=c*cp; ti[i]=c*sp; tw[i]=fmaf(w,m,1e-8f);
}

// retrieval + mix + LayerNorm; one row (b,s) per block; bf16 output
__global__ __launch_bounds__(256) void retrieve_ln_k(
    const float* __restrict__ tr, const float* __restrict__ ti, const float* __restrict__ tw,
    const float* __restrict__ phi, const float* __restrict__ qadj, const float* __restrict__ mix,
    const float* __restrict__ ln_g, const float* __restrict__ ln_b, ushort* __restrict__ outp)
{
    int row = blockIdx.x;
    size_t base  = (size_t)row*DD;
    size_t mbase = (size_t)row*D2;
    float vals[4];
    float sum=0.f, sumsq=0.f;
    #pragma unroll
    for(int k=0;k<4;k++){
        int d = threadIdx.x + k*256;
        float inv = rsqrtf(tw[base+d]);
        float mr = tr[base+d]*inv, mi = ti[base+d]*inv;
        float qp = phi[base+d] + qadj[base+d];
        float sq, cq; sincosf(qp, &sq, &cq);
        float rr = mr*cq + mi*sq;
        float ri = mi*cq - mr*sq;
        float ret = mix[mbase+d]*rr + mix[mbase+DD+d]*ri;
        vals[k]=ret; sum+=ret; sumsq = fmaf(ret,ret,sumsq);
    }
    #pragma unroll
    for(int off=32;off;off>>=1){
        sum   += __shfl_down(sum,off);
        sumsq += __shfl_down(sumsq,off);
    }
    __shared__ float red[8];
    int lane = threadIdx.x & 63, wid = threadIdx.x >> 6;
    if(lane==0){ red[wid]=sum; red[4+wid]=sumsq; }
    __syncthreads();
    sum   = red[0]+red[1]+red[2]+red[3];
    sumsq = red[4]+red[5]+red[6]+red[7];
    float mu  = sum * (1.0f/DD);
    float var = sumsq*(1.0f/DD) - mu*mu;
    float rstd = rsqrtf(var + 1e-5f);
    #pragma unroll
    for(int k=0;k<4;k++){
        int d = threadIdx.x + k*256;
        outp[base+d] = f2bf((vals[k]-mu)*rstd*ln_g[d] + ln_b[d]);
    }
}

extern "C" void kernel_launch(void* const* d_in, const int* in_sizes, int n_in,
                              void* d_out, int out_size, void* d_ws, size_t ws_size,
                              hipStream_t stream)
{
    const float* x     = (const float*)d_in[0];
    const float* w_pt1 = (const float*)d_in[1];
    const float* b_pt1 = (const float*)d_in[2];
    const float* w_pt2 = (const float*)d_in[3];
    const float* b_pt2 = (const float*)d_in[4];
    const float* iscale= (const float*)d_in[5];
    const float* w_wg  = (const float*)d_in[6];
    const float* b_wg  = (const float*)d_in[7];
    const float* gtemp = (const float*)d_in[8];
    const float* w_mag = (const float*)d_in[9];
    const float* b_mag = (const float*)d_in[10];
    const float* w_q1  = (const float*)d_in[11];
    const float* b_q1  = (const float*)d_in[12];
    const float* w_q2  = (const float*)d_in[13];
    const float* b_q2  = (const float*)d_in[14];
    const float* w_mix = (const float*)d_in[15];
    const float* b_mix = (const float*)d_in[16];
    const float* ln_g  = (const float*)d_in[17];
    const float* ln_b  = (const float*)d_in[18];
    const float* w_o1  = (const float*)d_in[19];
    const float* b_o1  = (const float*)d_in[20];
    const float* w_o2  = (const float*)d_in[21];
    const float* b_o2  = (const float*)d_in[22];
    float* out = (float*)d_out;

    float* ws = (float*)d_ws;
    const size_t SZ = (size_t)MTOT*DD;     // 4M
    float* pd   = ws;                      // SZ   (becomes phi)
    float* wgf  = ws + SZ;                 // SZ   (later: Hob bf16)
    float* magf = ws + 2*SZ;               // SZ   (later: lnb bf16)
    float* qadj = ws + 3*SZ;               // SZ
    float* mixb = ws + 4*SZ;               // 2SZ
    float* twf  = ws + 6*SZ;               // SZ
    float* trf  = ws + 7*SZ;               // SZ (first: H1b bf16 2SZ ushorts)
    ushort* H1b = (ushort*)(ws + 7*SZ);
    float* tif  = ws + 8*SZ;               // SZ (first: xb + Hqb bf16)
    ushort* xb  = (ushort*)(ws + 8*SZ);    // SZ ushorts
    ushort* Hqb = xb + SZ;                 // SZ ushorts
    ushort* wtu = (ushort*)(ws + 9*SZ);    // 12M ushorts
    float* csum_phi = ws + 9*SZ + 6*1024*1024;      // 32K floats
    float* csum_tri = csum_phi + (size_t)BB*NC*DD;  // 96K floats
    ushort* lnb = (ushort*)magf;
    ushort* Hob = (ushort*)wgf;

    ushort* wt_pt1 = wtu;                  // [2048][1024]
    ushort* wt_pt2 = wtu + 2*1024*1024;    // [1024][2048]
    ushort* wt_wg  = wtu + 4*1024*1024;
    ushort* wt_mag = wtu + 5*1024*1024;
    ushort* wt_q1  = wtu + 6*1024*1024;
    ushort* wt_q2  = wtu + 7*1024*1024;
    ushort* wt_mix = wtu + 8*1024*1024;    // [2048][1024]
    ushort* wt_o1  = wtu + 10*1024*1024;
    ushort* wt_o2  = wtu + 11*1024*1024;

    dim3 blk(256);
    // 0. conversions
    cvt_bf16_k<<<dim3(SZ/2048), blk, 0, stream>>>(x, xb);
    tcvt_k<<<dim3(2048/32, 1024/32), blk, 0, stream>>>(w_pt1, wt_pt1, 1024, 2048);
    tcvt_k<<<dim3(1024/32, 2048/32), blk, 0, stream>>>(w_pt2, wt_pt2, 2048, 1024);
    tcvt_k<<<dim3(32, 32), blk, 0, stream>>>(w_wg,  wt_wg,  1024, 1024);
    tcvt_k<<<dim3(32, 32), blk, 0, stream>>>(w_mag, wt_mag, 1024, 1024);
    tcvt_k<<<dim3(32, 32), blk, 0, stream>>>(w_q1,  wt_q1,  1024, 1024);
    tcvt_k<<<dim3(32, 32), blk, 0, stream>>>(w_q2,  wt_q2,  1024, 1024);
    tcvt_k<<<dim3(2048/32, 1024/32), blk, 0, stream>>>(w_mix, wt_mix, 1024, 2048);
    tcvt_k<<<dim3(32, 32), blk, 0, stream>>>(w_o1,  wt_o1,  1024, 1024);
    tcvt_k<<<dim3(32, 32), blk, 0, stream>>>(w_o2,  wt_o2,  1024, 1024);
    // 1. H1 = gelu(x @ w_pt1 + b) -> bf16
    mgemm_k<1,false,true><<<dim3(16,32), blk, 0, stream>>>(xb, wt_pt1, b_pt1, nullptr, nullptr, H1b, D2, DD);
    // 2. pd = H1 @ w_pt2 + b
    mgemm_k<0,false,false><<<dim3(8,32), blk, 0, stream>>>(H1b, wt_pt2, b_pt2, nullptr, nullptr, pd, DD, D2);
    // 3-5. wg / mag / Hq batched
    mgemm_z3_k<<<dim3(8,32,3), blk, 0, stream>>>(xb, wt_wg, wt_mag, wt_q1, b_wg, b_mag, b_q1,
                                                 gtemp, wgf, magf, Hqb, DD, DD);
    // 6. qadj = Hq @ w_q2 + b
    mgemm_k<0,false,false><<<dim3(8,32), blk, 0, stream>>>(Hqb, wt_q2, b_q2, nullptr, nullptr, qadj, DD, DD);
    // 7. mix = sigmoid(x @ w_mix + b)
    mgemm_k<2,false,false><<<dim3(16,32), blk, 0, stream>>>(xb, wt_mix, b_mix, nullptr, nullptr, mixb, D2, DD);
    // 8. phi = cumsum(pd * |iscale|) in place
    scan1_phi_k<<<dim3(DD/256, NC, BB), blk, 0, stream>>>(pd, iscale, csum_phi);
    scan2_k<<<dim3((BB*DD+255)/256), blk, 0, stream>>>(csum_phi, BB*DD);
    scan3_phi_k<<<dim3(DD/256, NC, BB), blk, 0, stream>>>(pd, iscale, csum_phi);
    // 9. elementwise terms
    elemw1_k<<<dim3(SZ/256), blk, 0, stream>>>(wgf, magf, x, pd, trf, tif, twf);
    // 10. triple cumsum in place
    scan1_tri_k<<<dim3(DD/256, NC, BB), blk, 0, stream>>>(trf, tif, twf, csum_tri);
    scan2_k<<<dim3((3*BB*DD+255)/256), blk, 0, stream>>>(csum_tri, 3*BB*DD);
    scan3_tri_k<<<dim3(DD/256, NC, BB), blk, 0, stream>>>(trf, tif, twf, csum_tri);
    // 11. retrieval + mix + LayerNorm -> bf16
    retrieve_ln_k<<<dim3(MTOT), blk, 0, stream>>>(trf, tif, twf, pd, qadj, mixb, ln_g, ln_b, lnb);
    // 12. Ho = gelu(ln @ w_o1 + b) -> bf16
    mgemm_k<1,false,true><<<dim3(8,32), blk, 0, stream>>>(lnb, wt_o1, b_o1, nullptr, nullptr, Hob, DD, DD);
    // 13. out = Ho @ w_o2 + b + x
    mgemm_k<0,true,false><<<dim3(8,32), blk, 0, stream>>>(Hob, wt_o2, b_o2, nullptr, x, out, DD, DD);
}